// Round 4
// baseline (960.554 us; speedup 1.0000x reference)
//
#include <hip/hip_runtime.h>
#include <math.h>

typedef __attribute__((ext_vector_type(8))) short short8;
typedef __attribute__((ext_vector_type(4))) float f32x4;

// fp32 -> bf16 bits, round-to-nearest-even
static __device__ __forceinline__ unsigned short f2bf(float f) {
  unsigned int u = __float_as_uint(f);
  u = u + 0x7fffu + ((u >> 16) & 1u);
  return (unsigned short)(u >> 16);
}

static __device__ __forceinline__ short8 pack_bf16(float4 v0, float4 v1) {
  short8 r;
  r[0] = (short)f2bf(v0.x); r[1] = (short)f2bf(v0.y);
  r[2] = (short)f2bf(v0.z); r[3] = (short)f2bf(v0.w);
  r[4] = (short)f2bf(v1.x); r[5] = (short)f2bf(v1.y);
  r[6] = (short)f2bf(v1.z); r[7] = (short)f2bf(v1.w);
  return r;
}

// ---------------- kernel 1: supT[batch][col][n] (bf16) = (x @ W)^T ----------------
__global__ __launch_bounds__(256) void support_kernel(
    const float* __restrict__ x, const float* __restrict__ w,
    unsigned short* __restrict__ supT, int N) {
  __shared__ float aT[64][65];
  __shared__ float bs[64][132];

  const int tid = threadIdx.x;
  const long long r0 = (long long)blockIdx.x * 64;
  const float* Ab = x + r0 * 128;
  const int tx = tid & 15;
  const int ty = tid >> 4;

  float acc[4][8] = {};
  const int ar = tid & 63, ak = (tid >> 6) * 16;
  const int bk = tid >> 2, bc = (tid & 3) * 32;

  for (int k0 = 0; k0 < 128; k0 += 64) {
    const float4* asrc = (const float4*)(Ab + (long long)ar * 128 + k0 + ak);
    #pragma unroll
    for (int j = 0; j < 4; ++j) {
      float4 v = asrc[j];
      aT[ak + 4*j + 0][ar] = v.x;
      aT[ak + 4*j + 1][ar] = v.y;
      aT[ak + 4*j + 2][ar] = v.z;
      aT[ak + 4*j + 3][ar] = v.w;
    }
    const float4* bsrc = (const float4*)(w + (long long)(k0 + bk) * 128 + bc);
    #pragma unroll
    for (int j = 0; j < 8; ++j) *(float4*)&bs[bk][bc + 4*j] = bsrc[j];
    __syncthreads();
    #pragma unroll 16
    for (int k = 0; k < 64; ++k) {
      float a[4], b[8];
      *(float4*)a      = *(const float4*)&aT[k][ty*4];
      *(float4*)&b[0]  = *(const float4*)&bs[k][tx*8];
      *(float4*)&b[4]  = *(const float4*)&bs[k][tx*8 + 4];
      #pragma unroll
      for (int i = 0; i < 4; ++i)
        #pragma unroll
        for (int j = 0; j < 8; ++j)
          acc[i][j] = fmaf(a[i], b[j], acc[i][j]);
    }
    __syncthreads();
  }
  const int batch = (int)(r0 / N);
  const int nloc = (int)(r0 % N) + ty * 4;
  #pragma unroll
  for (int j = 0; j < 8; ++j) {
    const int col = tx * 8 + j;
    ushort4 pv;
    pv.x = f2bf(acc[0][j]); pv.y = f2bf(acc[1][j]);
    pv.z = f2bf(acc[2][j]); pv.w = f2bf(acc[3][j]);
    *(ushort4*)&supT[(size_t)batch * 128 * N + (size_t)col * N + nloc] = pv;
  }
}

// ---------------- kernel 2: out = LIF(adj @ support + bias) ----------------
// Barrier-free, LDS-free. Wave = 16 rows x 64 cols; block = 4 waves = 32x128.
// A-fragments built straight from global fp32 (cvt in regs); B from L2/LLC-
// resident supT (bf16, k-contiguous). Depth-1 register pipeline: loads for
// k-step i+1 issue before the MFMAs of step i, keeping 6 wave-loads in flight.
__global__ __launch_bounds__(256) void spike_gemm_kernel(
    const float* __restrict__ adj, const unsigned short* __restrict__ supT,
    const float* __restrict__ bias, const int* __restrict__ tsp,
    float* __restrict__ out, int N) {
  const int tid = threadIdx.x;
  const int lane = tid & 63;
  const int wave = tid >> 6;             // waves 0/1: rows n0..+15, 2/3: n0+16..+31
  const int batch = blockIdx.y;
  const int n0 = blockIdx.x * 32;

  const int fm = lane & 15;              // MFMA m/n index
  const int kg = lane >> 4;              // MFMA k-group

  const int arow = n0 + (wave >> 1) * 16 + fm;
  const int cbase = (wave & 1) * 64;     // this wave's 64-col range

  const float* ap = adj + ((size_t)batch * N + arow) * N + kg * 8;
  const unsigned short* Bk = supT + (size_t)batch * 128 * N + kg * 8;
  const unsigned short* bp0 = Bk + (size_t)(cbase +  0 + fm) * N;
  const unsigned short* bp1 = Bk + (size_t)(cbase + 16 + fm) * N;
  const unsigned short* bp2 = Bk + (size_t)(cbase + 32 + fm) * N;
  const unsigned short* bp3 = Bk + (size_t)(cbase + 48 + fm) * N;

  f32x4 acc[4] = {};
  const int NK = N / 32;                 // 32-K steps

  // prologue: k-step 0 loads
  float4 a0 = *(const float4*)(ap);
  float4 a1 = *(const float4*)(ap + 4);
  uint4 b0 = *(const uint4*)(bp0);
  uint4 b1 = *(const uint4*)(bp1);
  uint4 b2 = *(const uint4*)(bp2);
  uint4 b3 = *(const uint4*)(bp3);

  #pragma unroll 4
  for (int ks = 0; ks < NK - 1; ++ks) {
    const int off = (ks + 1) * 32;
    // issue next k-step's loads first (A: HBM ~900cyc, B: L2/LLC)
    float4 na0 = *(const float4*)(ap + off);
    float4 na1 = *(const float4*)(ap + off + 4);
    uint4 nb0 = *(const uint4*)(bp0 + off);
    uint4 nb1 = *(const uint4*)(bp1 + off);
    uint4 nb2 = *(const uint4*)(bp2 + off);
    uint4 nb3 = *(const uint4*)(bp3 + off);

    short8 a = pack_bf16(a0, a1);
    acc[0] = __builtin_amdgcn_mfma_f32_16x16x32_bf16(a, *(const short8*)&b0, acc[0], 0, 0, 0);
    acc[1] = __builtin_amdgcn_mfma_f32_16x16x32_bf16(a, *(const short8*)&b1, acc[1], 0, 0, 0);
    acc[2] = __builtin_amdgcn_mfma_f32_16x16x32_bf16(a, *(const short8*)&b2, acc[2], 0, 0, 0);
    acc[3] = __builtin_amdgcn_mfma_f32_16x16x32_bf16(a, *(const short8*)&b3, acc[3], 0, 0, 0);

    a0 = na0; a1 = na1;
    b0 = nb0; b1 = nb1; b2 = nb2; b3 = nb3;
  }
  // peeled last k-step
  {
    short8 a = pack_bf16(a0, a1);
    acc[0] = __builtin_amdgcn_mfma_f32_16x16x32_bf16(a, *(const short8*)&b0, acc[0], 0, 0, 0);
    acc[1] = __builtin_amdgcn_mfma_f32_16x16x32_bf16(a, *(const short8*)&b1, acc[1], 0, 0, 0);
    acc[2] = __builtin_amdgcn_mfma_f32_16x16x32_bf16(a, *(const short8*)&b2, acc[2], 0, 0, 0);
    acc[3] = __builtin_amdgcn_mfma_f32_16x16x32_bf16(a, *(const short8*)&b3, acc[3], 0, 0, 0);
  }

  // ---- epilogue: adaptive-LIF recurrence, exact reference op order ----
  const int T = *tsp;
  #pragma unroll
  for (int ct = 0; ct < 4; ++ct) {
    const int col = cbase + ct * 16 + fm;
    const float bv = bias[col];
    #pragma unroll
    for (int i = 0; i < 4; ++i) {
      float I = acc[ct][i] + bv;
      float v = 0.0f, th = 1.0f, sacc = 0.0f;
      for (int t = 0; t < T; ++t) {
        v = v * 0.95f + I;                       // 1 - 1/tau_mem
        float u = v - th;
        float sig = 1.0f / (1.0f + expf(-4.0f * u));
        float hard = (u >= 0.0f) ? 1.0f : 0.0f;
        float s = (hard - sig) + sig;            // straight-through fwd
        sacc += s;
        v = v * (1.0f - s);
        th = th + (1.0f - th) / 60.0f + 0.1f * s;
      }
      const int row = n0 + (wave >> 1) * 16 + kg * 4 + i;
      out[((size_t)batch * N + row) * 128 + col] = sacc / (float)T;
    }
  }
}

extern "C" void kernel_launch(void* const* d_in, const int* in_sizes, int n_in,
                              void* d_out, int out_size, void* d_ws, size_t ws_size,
                              hipStream_t stream) {
  const float* x    = (const float*)d_in[0];
  const float* adj  = (const float*)d_in[1];
  const float* w    = (const float*)d_in[2];
  const float* bias = (const float*)d_in[3];
  const int*   tsp  = (const int*)d_in[4];
  float* out = (float*)d_out;
  unsigned short* supT = (unsigned short*)d_ws;  // 4 MB

  const long long sz_x = in_sizes[0];
  const long long sz_adj = in_sizes[1];
  const int N = (int)(sz_adj / sz_x * 128);
  const int B = (int)(sz_x / ((long long)N * 128));
  const int rows = B * N;

  support_kernel<<<rows / 64, 256, 0, stream>>>(x, w, supT, N);
  spike_gemm_kernel<<<dim3(N / 32, B), 256, 0, stream>>>(adj, supT, bias, tsp, out, N);
}